// Round 1
// baseline (44.359 us; speedup 1.0000x reference)
//
#include <hip/hip_runtime.h>

#define NTAGS 5
#define BB 8192
#define TT 512
#define WSTRIDE 12   // floats per worker record (48 B, float4-aligned)

// Phase 1: worker w = b*CC + c computes the 3x3 linear-domain transfer matrix
// (or, for c==0, the propagated init vector) for timesteps [c*LL, (c+1)*LL).
// Record layout (12 floats): M00..M22 (or v0,v1,v2), [9]=logscale.
template<int CC>
__global__ __launch_bounds__(256) void crf_scan(const float* __restrict__ feats,
                                                const float* __restrict__ trans,
                                                float* __restrict__ ws) {
    constexpr int LL = TT / CC;       // steps per chunk
    constexpr int G  = LL / 4;        // groups of 4 steps (20 floats = 5 float4)
    int w = blockIdx.x * 256 + threadIdx.x;
    int b = w / CC;
    int c = w & (CC - 1);

    // E = exp(trans) over tags {0,1,2}; trans is [next*5 + prev]
    float E00 = __expf(trans[0]),  E01 = __expf(trans[1]),  E02 = __expf(trans[2]);
    float E10 = __expf(trans[5]),  E11 = __expf(trans[6]),  E12 = __expf(trans[7]);
    float E20 = __expf(trans[10]), E21 = __expf(trans[11]), E22 = __expf(trans[12]);

    const float* fp = feats + ((size_t)b * TT + (size_t)c * LL) * NTAGS;

    float r0=0,r1=0,r2=0,r3=0,r4=0,r5=0,r6=0,r7=0,r8=0;
    float ls = 0.0f;

    if (c == 0) {
        // vector path: t=0 init from START column, then matvec steps
        float EC0 = __expf(trans[3]), EC1 = __expf(trans[8]), EC2 = __expf(trans[13]);
        float v0 = 0.f, v1 = 0.f, v2 = 0.f;
        #pragma unroll 4
        for (int g = 0; g < G; ++g) {
            const float4* q = (const float4*)(fp + g * 20);
            float4 a0=q[0], a1=q[1], a2=q[2], a3=q[3], a4=q[4];
            float f[20];
            f[0]=a0.x;  f[1]=a0.y;  f[2]=a0.z;  f[3]=a0.w;
            f[4]=a1.x;  f[5]=a1.y;  f[6]=a1.z;  f[7]=a1.w;
            f[8]=a2.x;  f[9]=a2.y;  f[10]=a2.z; f[11]=a2.w;
            f[12]=a3.x; f[13]=a3.y; f[14]=a3.z; f[15]=a3.w;
            f[16]=a4.x; f[17]=a4.y; f[18]=a4.z; f[19]=a4.w;
            #pragma unroll
            for (int s = 0; s < 4; ++s) {
                float e0 = __expf(f[s*5+0]);
                float e1 = __expf(f[s*5+1]);
                float e2 = __expf(f[s*5+2]);
                if (g == 0 && s == 0) {
                    v0 = e0 * EC0; v1 = e1 * EC1; v2 = e2 * EC2;
                } else {
                    float n0 = e0 * (E00*v0 + E01*v1 + E02*v2);
                    float n1 = e1 * (E10*v0 + E11*v1 + E12*v2);
                    float n2 = e2 * (E20*v0 + E21*v1 + E22*v2);
                    v0 = n0; v1 = n1; v2 = n2;
                }
            }
            float m = fmaxf(fmaxf(fmaxf(v0, v1), v2), 1e-30f);
            float inv = 1.0f / m;
            v0 *= inv; v1 *= inv; v2 *= inv;
            ls += __logf(m);
        }
        r0 = v0; r1 = v1; r2 = v2;
    } else {
        // matrix path: accumulate M <- D(e_t) * E * M
        float M00=1,M01=0,M02=0, M10=0,M11=1,M12=0, M20=0,M21=0,M22=1;
        #pragma unroll 4
        for (int g = 0; g < G; ++g) {
            const float4* q = (const float4*)(fp + g * 20);
            float4 a0=q[0], a1=q[1], a2=q[2], a3=q[3], a4=q[4];
            float f[20];
            f[0]=a0.x;  f[1]=a0.y;  f[2]=a0.z;  f[3]=a0.w;
            f[4]=a1.x;  f[5]=a1.y;  f[6]=a1.z;  f[7]=a1.w;
            f[8]=a2.x;  f[9]=a2.y;  f[10]=a2.z; f[11]=a2.w;
            f[12]=a3.x; f[13]=a3.y; f[14]=a3.z; f[15]=a3.w;
            f[16]=a4.x; f[17]=a4.y; f[18]=a4.z; f[19]=a4.w;
            #pragma unroll
            for (int s = 0; s < 4; ++s) {
                float e0 = __expf(f[s*5+0]);
                float e1 = __expf(f[s*5+1]);
                float e2 = __expf(f[s*5+2]);
                float N00 = e0*(E00*M00 + E01*M10 + E02*M20);
                float N01 = e0*(E00*M01 + E01*M11 + E02*M21);
                float N02 = e0*(E00*M02 + E01*M12 + E02*M22);
                float N10 = e1*(E10*M00 + E11*M10 + E12*M20);
                float N11 = e1*(E10*M01 + E11*M11 + E12*M21);
                float N12 = e1*(E10*M02 + E11*M12 + E12*M22);
                float N20 = e2*(E20*M00 + E21*M10 + E22*M20);
                float N21 = e2*(E20*M01 + E21*M11 + E22*M21);
                float N22 = e2*(E20*M02 + E21*M12 + E22*M22);
                M00=N00; M01=N01; M02=N02;
                M10=N10; M11=N11; M12=N12;
                M20=N20; M21=N21; M22=N22;
            }
            float m = fmaxf(fmaxf(fmaxf(M00,M01),fmaxf(M02,M10)),
                            fmaxf(fmaxf(M11,M12),fmaxf(fmaxf(M20,M21),M22)));
            m = fmaxf(m, 1e-30f);
            float inv = 1.0f / m;
            M00*=inv; M01*=inv; M02*=inv;
            M10*=inv; M11*=inv; M12*=inv;
            M20*=inv; M21*=inv; M22*=inv;
            ls += __logf(m);
        }
        r0=M00; r1=M01; r2=M02; r3=M10; r4=M11; r5=M12; r6=M20; r7=M21; r8=M22;
    }

    float4* o = (float4*)(ws + (size_t)w * WSTRIDE);
    o[0] = make_float4(r0, r1, r2, r3);
    o[1] = make_float4(r4, r5, r6, r7);
    o[2] = make_float4(r8, ls, 0.0f, 0.0f);
}

// Phase 2: per sequence, chain chunk records in time order and finish with the
// STOP-row terminal log-sum.
template<int CC>
__global__ __launch_bounds__(256) void crf_combine(const float* __restrict__ ws,
                                                   const float* __restrict__ trans,
                                                   float* __restrict__ out) {
    int b = blockIdx.x * 256 + threadIdx.x;
    const float4* rec = (const float4*)(ws + (size_t)b * CC * WSTRIDE);
    float4 q0 = rec[0];
    float4 q2 = rec[2];
    float v0 = q0.x, v1 = q0.y, v2 = q0.z;
    float ls = q2.y;
    #pragma unroll 4
    for (int c = 1; c < CC; ++c) {
        const float4* mr = (const float4*)(ws + ((size_t)b * CC + c) * WSTRIDE);
        float4 m0 = mr[0], m1 = mr[1], m2 = mr[2];
        float n0 = m0.x*v0 + m0.y*v1 + m0.z*v2;
        float n1 = m0.w*v0 + m1.x*v1 + m1.y*v2;
        float n2 = m1.z*v0 + m1.w*v1 + m2.x*v2;
        ls += m2.y;
        float mm = fmaxf(fmaxf(fmaxf(n0, n1), n2), 1e-30f);
        float inv = 1.0f / mm;
        v0 = n0*inv; v1 = n1*inv; v2 = n2*inv;
        ls += __logf(mm);
    }
    float S0 = __expf(trans[20]), S1 = __expf(trans[21]), S2 = __expf(trans[22]);
    out[b] = __logf(S0*v0 + S1*v1 + S2*v2) + ls;
}

extern "C" void kernel_launch(void* const* d_in, const int* in_sizes, int n_in,
                              void* d_out, int out_size, void* d_ws, size_t ws_size,
                              hipStream_t stream) {
    const float* feats = (const float*)d_in[0];
    const float* trans = (const float*)d_in[1];
    float* out = (float*)d_out;
    float* ws  = (float*)d_ws;

    auto need = [](int cc) { return (size_t)BB * cc * WSTRIDE * sizeof(float); };

    if (ws_size >= need(32)) {
        constexpr int CC = 32;
        crf_scan<CC><<<BB * CC / 256, 256, 0, stream>>>(feats, trans, ws);
        crf_combine<CC><<<BB / 256, 256, 0, stream>>>(ws, trans, out);
    } else if (ws_size >= need(16)) {
        constexpr int CC = 16;
        crf_scan<CC><<<BB * CC / 256, 256, 0, stream>>>(feats, trans, ws);
        crf_combine<CC><<<BB / 256, 256, 0, stream>>>(ws, trans, out);
    } else if (ws_size >= need(8)) {
        constexpr int CC = 8;
        crf_scan<CC><<<BB * CC / 256, 256, 0, stream>>>(feats, trans, ws);
        crf_combine<CC><<<BB / 256, 256, 0, stream>>>(ws, trans, out);
    } else {
        // minimal-workspace fallback: one chunk per sequence (vector path only)
        constexpr int CC = 1;
        crf_scan<CC><<<BB * CC / 256, 256, 0, stream>>>(feats, trans, ws);
        crf_combine<CC><<<BB / 256, 256, 0, stream>>>(ws, trans, out);
    }
}

// Round 2
// 26.876 us; speedup vs baseline: 1.6505x; 1.6505x over previous
//
#include <hip/hip_runtime.h>

#define BB 8192
#define TT 512
#define NTAGS 5
#define SPB 4          // sequences per block (one per wave)
#define LL  8          // timesteps per chunk (per lane)
#define SEQ4 704       // float4 stride per sequence in LDS (64 chunks * 11)

// One fused kernel: coalesced LDS staging -> per-lane 3x3 transfer matrix over
// 8 timesteps (linear domain, exp(trans) precomputed) -> 6-level shfl_xor
// butterfly composing the 64 matrices in time order -> STOP-row terminal.
__global__ __launch_bounds__(256, 3) void crf_fused(const float* __restrict__ feats,
                                                    const float* __restrict__ trans,
                                                    float* __restrict__ out) {
    __shared__ float4 sm[SPB * SEQ4];   // 45056 B

    const int tid = threadIdx.x;
    const int b0  = blockIdx.x * SPB;

    // ---- coalesced staging: 2560 float4 per block, 10 per thread ----
    const float4* gp = (const float4*)(feats + (size_t)b0 * TT * NTAGS);
    #pragma unroll
    for (int i = 0; i < 10; ++i) {
        int q = i * 256 + tid;
        float4 val = gp[q];
        int sq = q / 640;           // 640 float4 per sequence
        int v  = q - sq * 640;
        int cc = v / 10;            // chunk
        int j  = v - cc * 10;       // float4 within chunk
        sm[sq * SEQ4 + cc * 11 + j] = val;
    }

    // ---- transitions (tags {0,1,2}; trans[next*5+prev]) ----
    const float E00 = __expf(trans[0]),  E01 = __expf(trans[1]),  E02 = __expf(trans[2]);
    const float E10 = __expf(trans[5]),  E11 = __expf(trans[6]),  E12 = __expf(trans[7]);
    const float E20 = __expf(trans[10]), E21 = __expf(trans[11]), E22 = __expf(trans[12]);

    const int lane = tid & 63;
    const int sq   = tid >> 6;

    // first-step factor: chunk 0 (lane 0) starts from the START column
    float G00, G01, G02, G10, G11, G12, G20, G21, G22;
    if (lane == 0) {
        float EC0 = __expf(trans[3]), EC1 = __expf(trans[8]), EC2 = __expf(trans[13]);
        G00 = G01 = G02 = EC0;
        G10 = G11 = G12 = EC1;
        G20 = G21 = G22 = EC2;
    } else {
        G00 = E00; G01 = E01; G02 = E02;
        G10 = E10; G11 = E11; G12 = E12;
        G20 = E20; G21 = E21; G22 = E22;
    }

    __syncthreads();

    // ---- read this lane's chunk (10 float4 = 8 steps x 5 tags) ----
    const float4* cp = &sm[sq * SEQ4 + lane * 11];
    float4 q0 = cp[0], q1 = cp[1], q2 = cp[2], q3 = cp[3], q4 = cp[4];
    float4 q5 = cp[5], q6 = cp[6], q7 = cp[7], q8 = cp[8], q9 = cp[9];

    float M00, M01, M02, M10, M11, M12, M20, M21, M22;
    float ls = 0.0f;

    // t0: M = D(e) * G
    {
        float e0 = __expf(q0.x), e1 = __expf(q0.y), e2 = __expf(q0.z);
        M00 = e0 * G00; M01 = e0 * G01; M02 = e0 * G02;
        M10 = e1 * G10; M11 = e1 * G11; M12 = e1 * G12;
        M20 = e2 * G20; M21 = e2 * G21; M22 = e2 * G22;
    }

#define CRF_STEP(FA, FB, FC) do {                                   \
        float e0 = __expf(FA), e1 = __expf(FB), e2 = __expf(FC);    \
        float N00 = e0 * (E00*M00 + E01*M10 + E02*M20);             \
        float N01 = e0 * (E00*M01 + E01*M11 + E02*M21);             \
        float N02 = e0 * (E00*M02 + E01*M12 + E02*M22);             \
        float N10 = e1 * (E10*M00 + E11*M10 + E12*M20);             \
        float N11 = e1 * (E10*M01 + E11*M11 + E12*M21);             \
        float N12 = e1 * (E10*M02 + E11*M12 + E12*M22);             \
        float N20 = e2 * (E20*M00 + E21*M10 + E22*M20);             \
        float N21 = e2 * (E20*M01 + E21*M11 + E22*M21);             \
        float N22 = e2 * (E20*M02 + E21*M12 + E22*M22);             \
        M00=N00; M01=N01; M02=N02;                                  \
        M10=N10; M11=N11; M12=N12;                                  \
        M20=N20; M21=N21; M22=N22;                                  \
    } while (0)

#define CRF_RENORM() do {                                           \
        float mx = fmaxf(fmaxf(fmaxf(M00,M01), fmaxf(M02,M10)),     \
                         fmaxf(fmaxf(M11,M12), fmaxf(fmaxf(M20,M21),M22))); \
        mx = fmaxf(mx, 1e-30f);                                     \
        float inv = 1.0f / mx;                                      \
        ls += __logf(mx);                                           \
        M00*=inv; M01*=inv; M02*=inv;                               \
        M10*=inv; M11*=inv; M12*=inv;                               \
        M20*=inv; M21*=inv; M22*=inv;                               \
    } while (0)

    CRF_STEP(q1.y, q1.z, q1.w);   // t1
    CRF_STEP(q2.z, q2.w, q3.x);   // t2
    CRF_STEP(q3.w, q4.x, q4.y);   // t3
    CRF_RENORM();
    CRF_STEP(q5.x, q5.y, q5.z);   // t4
    CRF_STEP(q6.y, q6.z, q6.w);   // t5
    CRF_STEP(q7.z, q7.w, q8.x);   // t6
    CRF_STEP(q8.w, q9.x, q9.y);   // t7
    CRF_RENORM();

    // ---- butterfly: compose 64 chunk matrices in time order ----
    #pragma unroll
    for (int d = 1; d < 64; d <<= 1) {
        float P00 = __shfl_xor(M00, d), P01 = __shfl_xor(M01, d), P02 = __shfl_xor(M02, d);
        float P10 = __shfl_xor(M10, d), P11 = __shfl_xor(M11, d), P12 = __shfl_xor(M12, d);
        float P20 = __shfl_xor(M20, d), P21 = __shfl_xor(M21, d), P22 = __shfl_xor(M22, d);
        float Pls = __shfl_xor(ls,  d);
        bool up = (lane & d) != 0;   // my block is the later one
        float A00 = up ? M00 : P00, A01 = up ? M01 : P01, A02 = up ? M02 : P02;
        float A10 = up ? M10 : P10, A11 = up ? M11 : P11, A12 = up ? M12 : P12;
        float A20 = up ? M20 : P20, A21 = up ? M21 : P21, A22 = up ? M22 : P22;
        float B00 = up ? P00 : M00, B01 = up ? P01 : M01, B02 = up ? P02 : M02;
        float B10 = up ? P10 : M10, B11 = up ? P11 : M11, B12 = up ? P12 : M12;
        float B20 = up ? P20 : M20, B21 = up ? P21 : M21, B22 = up ? P22 : M22;
        M00 = A00*B00 + A01*B10 + A02*B20;
        M01 = A00*B01 + A01*B11 + A02*B21;
        M02 = A00*B02 + A01*B12 + A02*B22;
        M10 = A10*B00 + A11*B10 + A12*B20;
        M11 = A10*B01 + A11*B11 + A12*B21;
        M12 = A10*B02 + A11*B12 + A12*B22;
        M20 = A20*B00 + A21*B10 + A22*B20;
        M21 = A20*B01 + A21*B11 + A22*B21;
        M22 = A20*B02 + A21*B12 + A22*B22;
        ls += Pls;
        CRF_RENORM();
    }

    // ---- terminal: column 0 holds M_total * v0 ----
    const float S0 = __expf(trans[20]), S1 = __expf(trans[21]), S2 = __expf(trans[22]);
    float r = S0 * M00 + S1 * M10 + S2 * M20;
    float res = __logf(r) + ls;
    if (lane == 0) out[b0 + sq] = res;

#undef CRF_STEP
#undef CRF_RENORM
}

extern "C" void kernel_launch(void* const* d_in, const int* in_sizes, int n_in,
                              void* d_out, int out_size, void* d_ws, size_t ws_size,
                              hipStream_t stream) {
    const float* feats = (const float*)d_in[0];
    const float* trans = (const float*)d_in[1];
    float* out = (float*)d_out;
    (void)d_ws; (void)ws_size;

    crf_fused<<<BB / SPB, 256, 0, stream>>>(feats, trans, out);
}

// Round 3
// 24.138 us; speedup vs baseline: 1.8378x; 1.1134x over previous
//
#include <hip/hip_runtime.h>

#define BB 8192
#define TT 512
#define SEQF 2560      // floats per sequence (512*5)
#define NWAVES 4       // waves per block
#define ITERS 4        // sequences per wave

// width-16 global -> LDS direct copy; LDS dest is wave-uniform base + lane*16,
// global src is per-lane (here: linear, so LDS image == global image).
__device__ __forceinline__ void gload_lds16(const float* g, float* l) {
    __builtin_amdgcn_global_load_lds(
        (__attribute__((address_space(1))) void*)g,
        (__attribute__((address_space(3))) void*)l, 16, 0, 0);
}

__global__ __launch_bounds__(256, 2) void crf_fused(const float* __restrict__ feats,
                                                    const float* __restrict__ trans,
                                                    float* __restrict__ out) {
    __shared__ __align__(16) float sm[2 * NWAVES * SEQF];   // 81920 B -> 2 blocks/CU

    const int tid  = threadIdx.x;
    const int lane = tid & 63;
    const int wv   = tid >> 6;
    const int seq0 = (blockIdx.x * NWAVES + wv) * ITERS;

    // exp(transitions) over live tags {0,1,2}; trans[next*5 + prev]
    const float E00 = __expf(trans[0]),  E01 = __expf(trans[1]),  E02 = __expf(trans[2]);
    const float E10 = __expf(trans[5]),  E11 = __expf(trans[6]),  E12 = __expf(trans[7]);
    const float E20 = __expf(trans[10]), E21 = __expf(trans[11]), E22 = __expf(trans[12]);
    const float S0  = __expf(trans[20]), S1  = __expf(trans[21]), S2  = __expf(trans[22]);

    // first-step factor: lane 0's chunk starts at t=0 (START column, replicated)
    float G00, G01, G02, G10, G11, G12, G20, G21, G22;
    if (lane == 0) {
        float C0 = __expf(trans[3]), C1 = __expf(trans[8]), C2 = __expf(trans[13]);
        G00 = G01 = G02 = C0;  G10 = G11 = G12 = C1;  G20 = G21 = G22 = C2;
    } else {
        G00 = E00; G01 = E01; G02 = E02;
        G10 = E10; G11 = E11; G12 = E12;
        G20 = E20; G21 = E21; G22 = E22;
    }

    // stage one sequence (10 KB) into buffer `buf` of this wave's LDS slot
    auto stage = [&](int buf, int s) {
        const float* g = feats + (size_t)s * SEQF + (size_t)lane * 4;
        float* l = &sm[(buf * NWAVES + wv) * SEQF];
        #pragma unroll
        for (int i = 0; i < 10; ++i)
            gload_lds16(g + i * 256, l + i * 256);
    };

    stage(0, seq0);

#define CRF_STEP(FA, FB, FC) do {                                   \
        float e0 = __expf(FA), e1 = __expf(FB), e2 = __expf(FC);    \
        float N00 = e0 * (E00*M00 + E01*M10 + E02*M20);             \
        float N01 = e0 * (E00*M01 + E01*M11 + E02*M21);             \
        float N02 = e0 * (E00*M02 + E01*M12 + E02*M22);             \
        float N10 = e1 * (E10*M00 + E11*M10 + E12*M20);             \
        float N11 = e1 * (E10*M01 + E11*M11 + E12*M21);             \
        float N12 = e1 * (E10*M02 + E11*M12 + E12*M22);             \
        float N20 = e2 * (E20*M00 + E21*M10 + E22*M20);             \
        float N21 = e2 * (E20*M01 + E21*M11 + E22*M21);             \
        float N22 = e2 * (E20*M02 + E21*M12 + E22*M22);             \
        M00=N00; M01=N01; M02=N02;                                  \
        M10=N10; M11=N11; M12=N12;                                  \
        M20=N20; M21=N21; M22=N22;                                  \
    } while (0)

    // exact power-of-two renorm: no divide, no log; ls counts exponent (units of ln2)
#define CRF_RENORM() do {                                           \
        float mx = fmaxf(fmaxf(fmaxf(M00,M01), fmaxf(M02,M10)),     \
                         fmaxf(fmaxf(M11,M12), fmaxf(fmaxf(M20,M21),M22))); \
        mx = fmaxf(mx, 1e-30f);                                     \
        int ee = (int)((__float_as_uint(mx) >> 23) & 0xffu) - 127;  \
        float sc = __uint_as_float((unsigned)(127 - ee) << 23);     \
        ls += (float)ee;                                            \
        M00*=sc; M01*=sc; M02*=sc;                                  \
        M10*=sc; M11*=sc; M12*=sc;                                  \
        M20*=sc; M21*=sc; M22*=sc;                                  \
    } while (0)

    // suffix-scan level: P = matrix of lane+D (later in time); M <- P * M
#define TREE_LEVEL(D) do {                                          \
        float P00=__shfl_down(M00,D), P01=__shfl_down(M01,D), P02=__shfl_down(M02,D); \
        float P10=__shfl_down(M10,D), P11=__shfl_down(M11,D), P12=__shfl_down(M12,D); \
        float P20=__shfl_down(M20,D), P21=__shfl_down(M21,D), P22=__shfl_down(M22,D); \
        float Pls=__shfl_down(ls, D);                               \
        float N00 = P00*M00 + P01*M10 + P02*M20;                    \
        float N01 = P00*M01 + P01*M11 + P02*M21;                    \
        float N02 = P00*M02 + P01*M12 + P02*M22;                    \
        float N10 = P10*M00 + P11*M10 + P12*M20;                    \
        float N11 = P10*M01 + P11*M11 + P12*M21;                    \
        float N12 = P10*M02 + P11*M12 + P12*M22;                    \
        float N20 = P20*M00 + P21*M10 + P22*M20;                    \
        float N21 = P20*M01 + P21*M11 + P22*M21;                    \
        float N22 = P20*M02 + P21*M12 + P22*M22;                    \
        M00=N00; M01=N01; M02=N02; M10=N10; M11=N11; M12=N12;       \
        M20=N20; M21=N21; M22=N22;                                  \
        ls += Pls;                                                  \
        CRF_RENORM();                                               \
    } while (0)

    for (int it = 0; it < ITERS; ++it) {
        // wait for this buffer's 10 loads (the only VMEM outstanding), then read
        asm volatile("s_waitcnt vmcnt(0)" ::: "memory");
        __builtin_amdgcn_sched_barrier(0);

        const float4* cp = (const float4*)(&sm[((it & 1) * NWAVES + wv) * SEQF]) + lane * 10;
        float4 q0=cp[0], q1=cp[1], q2=cp[2], q3=cp[3], q4=cp[4];
        float4 q5=cp[5], q6=cp[6], q7=cp[7], q8=cp[8], q9=cp[9];

        // prefetch next sequence into the other buffer; stays in flight under compute
        if (it + 1 < ITERS) stage((it + 1) & 1, seq0 + it + 1);

        float M00, M01, M02, M10, M11, M12, M20, M21, M22;
        float ls = 0.0f;

        {   // t0: M = D(e) * G
            float e0 = __expf(q0.x), e1 = __expf(q0.y), e2 = __expf(q0.z);
            M00 = e0*G00; M01 = e0*G01; M02 = e0*G02;
            M10 = e1*G10; M11 = e1*G11; M12 = e1*G12;
            M20 = e2*G20; M21 = e2*G21; M22 = e2*G22;
        }
        CRF_STEP(q1.y, q1.z, q1.w);   // t1
        CRF_STEP(q2.z, q2.w, q3.x);   // t2
        CRF_STEP(q3.w, q4.x, q4.y);   // t3
        CRF_RENORM();
        CRF_STEP(q5.x, q5.y, q5.z);   // t4
        CRF_STEP(q6.y, q6.z, q6.w);   // t5
        CRF_STEP(q7.z, q7.w, q8.x);   // t6
        CRF_STEP(q8.w, q9.x, q9.y);   // t7
        CRF_RENORM();

        TREE_LEVEL(1);  TREE_LEVEL(2);  TREE_LEVEL(4);
        TREE_LEVEL(8);  TREE_LEVEL(16); TREE_LEVEL(32);

        // lane 0: column 0 = full product applied to START-init vector
        float r = S0*M00 + S1*M10 + S2*M20;
        float res = __logf(r) + ls * 0.69314718055994531f;
        if (lane == 0) out[seq0 + it] = res;
    }

#undef CRF_STEP
#undef CRF_RENORM
#undef TREE_LEVEL
}

extern "C" void kernel_launch(void* const* d_in, const int* in_sizes, int n_in,
                              void* d_out, int out_size, void* d_ws, size_t ws_size,
                              hipStream_t stream) {
    const float* feats = (const float*)d_in[0];
    const float* trans = (const float*)d_in[1];
    float* out = (float*)d_out;
    (void)d_ws; (void)ws_size;

    crf_fused<<<BB / (NWAVES * ITERS), 256, 0, stream>>>(feats, trans, out);
}

// Round 4
// 20.953 us; speedup vs baseline: 2.1171x; 1.1520x over previous
//
#include <hip/hip_runtime.h>

#define BB 8192
#define SEQF 2560      // floats per sequence (512*5)

__device__ __forceinline__ float rfl(float x) {
    return __int_as_float(__builtin_amdgcn_readfirstlane(__float_as_int(x)));
}

// One wave = 2 sequences. Lane owns an 8-timestep chunk (40 floats, registers).
// Linear-domain 3x3 transfer matrices, power-of-two renorm, shfl_down suffix tree.
__global__ __launch_bounds__(256, 4) void crf_fused(const float* __restrict__ feats,
                                                    const float* __restrict__ trans,
                                                    float* __restrict__ out) {
    const int tid  = threadIdx.x;
    const int lane = tid & 63;
    const int gw   = blockIdx.x * 4 + (tid >> 6);
    const int s0   = gw * 2;

    // ---- issue ALL global loads up front (A then B; FIFO order is the pipeline) ----
    const float4* pA = (const float4*)(feats + (size_t)s0 * SEQF) + lane * 10;
    const float4* pB = pA + (SEQF / 4);   // next sequence, same lane chunk
    float4 a0=pA[0], a1=pA[1], a2=pA[2], a3=pA[3], a4=pA[4];
    float4 a5=pA[5], a6=pA[6], a7=pA[7], a8=pA[8], a9=pA[9];
    float4 b0=pB[0], b1=pB[1], b2=pB[2], b3=pB[3], b4=pB[4];
    float4 b5=pB[5], b6=pB[6], b7=pB[7], b8=pB[8], b9=pB[9];
    __builtin_amdgcn_sched_barrier(0);   // don't sink loads below compute

    // ---- uniform transition factors -> SGPRs ----
    const float E00=rfl(__expf(trans[0])),  E01=rfl(__expf(trans[1])),  E02=rfl(__expf(trans[2]));
    const float E10=rfl(__expf(trans[5])),  E11=rfl(__expf(trans[6])),  E12=rfl(__expf(trans[7]));
    const float E20=rfl(__expf(trans[10])), E21=rfl(__expf(trans[11])), E22=rfl(__expf(trans[12]));
    const float C0 =rfl(__expf(trans[3])),  C1 =rfl(__expf(trans[8])),  C2 =rfl(__expf(trans[13]));
    const float S0 =rfl(__expf(trans[20])), S1 =rfl(__expf(trans[21])), S2 =rfl(__expf(trans[22]));

#define CRF_STEP(FA, FB, FC) do {                                   \
        float e0 = __expf(FA), e1 = __expf(FB), e2 = __expf(FC);    \
        float N00 = e0 * (E00*M00 + E01*M10 + E02*M20);             \
        float N01 = e0 * (E00*M01 + E01*M11 + E02*M21);             \
        float N02 = e0 * (E00*M02 + E01*M12 + E02*M22);             \
        float N10 = e1 * (E10*M00 + E11*M10 + E12*M20);             \
        float N11 = e1 * (E10*M01 + E11*M11 + E12*M21);             \
        float N12 = e1 * (E10*M02 + E11*M12 + E12*M22);             \
        float N20 = e2 * (E20*M00 + E21*M10 + E22*M20);             \
        float N21 = e2 * (E20*M01 + E21*M11 + E22*M21);             \
        float N22 = e2 * (E20*M02 + E21*M12 + E22*M22);             \
        M00=N00; M01=N01; M02=N02;                                  \
        M10=N10; M11=N11; M12=N12;                                  \
        M20=N20; M21=N21; M22=N22;                                  \
    } while (0)

    // exact power-of-two renorm: ls counts the exponent (units of ln2)
#define CRF_RENORM() do {                                           \
        float mx = fmaxf(fmaxf(fmaxf(M00,M01), fmaxf(M02,M10)),     \
                         fmaxf(fmaxf(M11,M12), fmaxf(fmaxf(M20,M21),M22))); \
        mx = fmaxf(mx, 1e-30f);                                     \
        int ee = (int)((__float_as_uint(mx) >> 23) & 0xffu) - 127;  \
        float sc = __uint_as_float((unsigned)(127 - ee) << 23);     \
        ls += (float)ee;                                            \
        M00*=sc; M01*=sc; M02*=sc;                                  \
        M10*=sc; M11*=sc; M12*=sc;                                  \
        M20*=sc; M21*=sc; M22*=sc;                                  \
    } while (0)

    // suffix-scan level: P = lane+D (later in time); M <- P * M
#define TREE_LEVEL(D) do {                                          \
        float P00=__shfl_down(M00,D), P01=__shfl_down(M01,D), P02=__shfl_down(M02,D); \
        float P10=__shfl_down(M10,D), P11=__shfl_down(M11,D), P12=__shfl_down(M12,D); \
        float P20=__shfl_down(M20,D), P21=__shfl_down(M21,D), P22=__shfl_down(M22,D); \
        float Pls=__shfl_down(ls, D);                               \
        float N00 = P00*M00 + P01*M10 + P02*M20;                    \
        float N01 = P00*M01 + P01*M11 + P02*M21;                    \
        float N02 = P00*M02 + P01*M12 + P02*M22;                    \
        float N10 = P10*M00 + P11*M10 + P12*M20;                    \
        float N11 = P10*M01 + P11*M11 + P12*M21;                    \
        float N12 = P10*M02 + P11*M12 + P12*M22;                    \
        float N20 = P20*M00 + P21*M10 + P22*M20;                    \
        float N21 = P20*M01 + P21*M11 + P22*M21;                    \
        float N22 = P20*M02 + P21*M12 + P22*M22;                    \
        M00=N00; M01=N01; M02=N02; M10=N10; M11=N11; M12=N12;       \
        M20=N20; M21=N21; M22=N22;                                  \
        ls += Pls;                                                  \
        CRF_RENORM();                                               \
    } while (0)

#define CRF_SEQ(q0,q1,q2,q3,q4,q5,q6,q7,q8,q9, OUTIDX) do {         \
        float M00, M01, M02, M10, M11, M12, M20, M21, M22;          \
        float ls = 0.0f;                                            \
        {   /* t0: interior chunks use E; lane 0 starts from START column */ \
            float e0 = __expf(q0.x), e1 = __expf(q0.y), e2 = __expf(q0.z); \
            M00 = e0*E00; M01 = e0*E01; M02 = e0*E02;               \
            M10 = e1*E10; M11 = e1*E11; M12 = e1*E12;               \
            M20 = e2*E20; M21 = e2*E21; M22 = e2*E22;               \
            if (lane == 0) {                                        \
                M00 = M01 = M02 = e0*C0;                            \
                M10 = M11 = M12 = e1*C1;                            \
                M20 = M21 = M22 = e2*C2;                            \
            }                                                       \
        }                                                           \
        CRF_STEP(q1.y, q1.z, q1.w);   /* t1 */                      \
        CRF_STEP(q2.z, q2.w, q3.x);   /* t2 */                      \
        CRF_STEP(q3.w, q4.x, q4.y);   /* t3 */                      \
        CRF_RENORM();                                               \
        CRF_STEP(q5.x, q5.y, q5.z);   /* t4 */                      \
        CRF_STEP(q6.y, q6.z, q6.w);   /* t5 */                      \
        CRF_STEP(q7.z, q7.w, q8.x);   /* t6 */                      \
        CRF_STEP(q8.w, q9.x, q9.y);   /* t7 */                      \
        CRF_RENORM();                                               \
        TREE_LEVEL(1);  TREE_LEVEL(2);  TREE_LEVEL(4);              \
        TREE_LEVEL(8);  TREE_LEVEL(16); TREE_LEVEL(32);             \
        float r = S0*M00 + S1*M10 + S2*M20;                         \
        float res = __logf(r) + ls * 0.69314718055994531f;          \
        if (lane == 0) out[OUTIDX] = res;                           \
    } while (0)

    CRF_SEQ(a0,a1,a2,a3,a4,a5,a6,a7,a8,a9, s0);
    CRF_SEQ(b0,b1,b2,b3,b4,b5,b6,b7,b8,b9, s0 + 1);

#undef CRF_STEP
#undef CRF_RENORM
#undef TREE_LEVEL
#undef CRF_SEQ
}

extern "C" void kernel_launch(void* const* d_in, const int* in_sizes, int n_in,
                              void* d_out, int out_size, void* d_ws, size_t ws_size,
                              hipStream_t stream) {
    const float* feats = (const float*)d_in[0];
    const float* trans = (const float*)d_in[1];
    float* out = (float*)d_out;
    (void)d_ws; (void)ws_size;

    crf_fused<<<BB / 8, 256, 0, stream>>>(feats, trans, out);
}

// Round 5
// 19.600 us; speedup vs baseline: 2.2632x; 1.0690x over previous
//
#include <hip/hip_runtime.h>

#define BB 8192
#define SEQF 2560      // floats per sequence (512*5)

__device__ __forceinline__ float rfl(float x) {
    return __int_as_float(__builtin_amdgcn_readfirstlane(__float_as_int(x)));
}

// One wave = 2 sequences: lanes 0-31 scan seq A, lanes 32-63 scan seq B.
// Each lane: 16 timesteps (80 contiguous floats) -> 3x3 linear-domain transfer
// matrix; one shared 5-level shfl_down suffix tree combines both halves.
__global__ __launch_bounds__(256, 4) void crf_fused(const float* __restrict__ feats,
                                                    const float* __restrict__ trans,
                                                    float* __restrict__ out) {
    const int tid  = threadIdx.x;
    const int lane = tid & 63;
    const int half = lane >> 5;      // which sequence of the pair
    const int cpos = lane & 31;      // chunk index within the sequence
    const int gw   = blockIdx.x * 4 + (tid >> 6);
    const int s0   = gw * 2;

    // ---- issue ALL 20 loads up front (contiguous 320 B per lane) ----
    const float4* p = (const float4*)(feats + (size_t)(s0 + half) * SEQF) + cpos * 20;
    float4 q0 =p[0],  q1 =p[1],  q2 =p[2],  q3 =p[3],  q4 =p[4];
    float4 q5 =p[5],  q6 =p[6],  q7 =p[7],  q8 =p[8],  q9 =p[9];
    float4 q10=p[10], q11=p[11], q12=p[12], q13=p[13], q14=p[14];
    float4 q15=p[15], q16=p[16], q17=p[17], q18=p[18], q19=p[19];
    __builtin_amdgcn_sched_barrier(0);   // don't sink loads below compute

    // ---- uniform transition factors -> SGPRs ----
    const float E00=rfl(__expf(trans[0])),  E01=rfl(__expf(trans[1])),  E02=rfl(__expf(trans[2]));
    const float E10=rfl(__expf(trans[5])),  E11=rfl(__expf(trans[6])),  E12=rfl(__expf(trans[7]));
    const float E20=rfl(__expf(trans[10])), E21=rfl(__expf(trans[11])), E22=rfl(__expf(trans[12]));
    const float C0 =rfl(__expf(trans[3])),  C1 =rfl(__expf(trans[8])),  C2 =rfl(__expf(trans[13]));
    const float S0 =rfl(__expf(trans[20])), S1 =rfl(__expf(trans[21])), S2 =rfl(__expf(trans[22]));

    // first-step factor: chunk 0 of each sequence starts from the START column
    const bool c0 = (cpos == 0);
    const float G00 = c0 ? C0 : E00, G01 = c0 ? C0 : E01, G02 = c0 ? C0 : E02;
    const float G10 = c0 ? C1 : E10, G11 = c0 ? C1 : E11, G12 = c0 ? C1 : E12;
    const float G20 = c0 ? C2 : E20, G21 = c0 ? C2 : E21, G22 = c0 ? C2 : E22;

#define CRF_STEP(FA, FB, FC) do {                                   \
        float e0 = __expf(FA), e1 = __expf(FB), e2 = __expf(FC);    \
        float N00 = e0 * (E00*M00 + E01*M10 + E02*M20);             \
        float N01 = e0 * (E00*M01 + E01*M11 + E02*M21);             \
        float N02 = e0 * (E00*M02 + E01*M12 + E02*M22);             \
        float N10 = e1 * (E10*M00 + E11*M10 + E12*M20);             \
        float N11 = e1 * (E10*M01 + E11*M11 + E12*M21);             \
        float N12 = e1 * (E10*M02 + E11*M12 + E12*M22);             \
        float N20 = e2 * (E20*M00 + E21*M10 + E22*M20);             \
        float N21 = e2 * (E20*M01 + E21*M11 + E22*M21);             \
        float N22 = e2 * (E20*M02 + E21*M12 + E22*M22);             \
        M00=N00; M01=N01; M02=N02;                                  \
        M10=N10; M11=N11; M12=N12;                                  \
        M20=N20; M21=N21; M22=N22;                                  \
    } while (0)

    // exact power-of-two renorm; ls counts the exponent (units of ln2)
#define CRF_RENORM() do {                                           \
        float mx = fmaxf(fmaxf(fmaxf(M00,M01), fmaxf(M02,M10)),     \
                         fmaxf(fmaxf(M11,M12), fmaxf(fmaxf(M20,M21),M22))); \
        mx = fmaxf(mx, 1e-30f);                                     \
        int ee = (int)((__float_as_uint(mx) >> 23) & 0xffu) - 127;  \
        float sc = __uint_as_float((unsigned)(127 - ee) << 23);     \
        ls += (float)ee;                                            \
        M00*=sc; M01*=sc; M02*=sc;                                  \
        M10*=sc; M11*=sc; M12*=sc;                                  \
        M20*=sc; M21*=sc; M22*=sc;                                  \
    } while (0)

    // suffix-scan level: P = lane+D (later in time); M <- P * M
#define TREE_LEVEL(D, RN) do {                                      \
        float P00=__shfl_down(M00,D), P01=__shfl_down(M01,D), P02=__shfl_down(M02,D); \
        float P10=__shfl_down(M10,D), P11=__shfl_down(M11,D), P12=__shfl_down(M12,D); \
        float P20=__shfl_down(M20,D), P21=__shfl_down(M21,D), P22=__shfl_down(M22,D); \
        float Pls=__shfl_down(ls, D);                               \
        float N00 = P00*M00 + P01*M10 + P02*M20;                    \
        float N01 = P00*M01 + P01*M11 + P02*M21;                    \
        float N02 = P00*M02 + P01*M12 + P02*M22;                    \
        float N10 = P10*M00 + P11*M10 + P12*M20;                    \
        float N11 = P10*M01 + P11*M11 + P12*M21;                    \
        float N12 = P10*M02 + P11*M12 + P12*M22;                    \
        float N20 = P20*M00 + P21*M10 + P22*M20;                    \
        float N21 = P20*M01 + P21*M11 + P22*M21;                    \
        float N22 = P20*M02 + P21*M12 + P22*M22;                    \
        M00=N00; M01=N01; M02=N02; M10=N10; M11=N11; M12=N12;       \
        M20=N20; M21=N21; M22=N22;                                  \
        ls += Pls;                                                  \
        if (RN) CRF_RENORM();                                       \
    } while (0)

    float M00, M01, M02, M10, M11, M12, M20, M21, M22;
    float ls = 0.0f;

    {   // t0: M = D(e) * G
        float e0 = __expf(q0.x), e1 = __expf(q0.y), e2 = __expf(q0.z);
        M00 = e0*G00; M01 = e0*G01; M02 = e0*G02;
        M10 = e1*G10; M11 = e1*G11; M12 = e1*G12;
        M20 = e2*G20; M21 = e2*G21; M22 = e2*G22;
    }
    CRF_STEP(q1.y,  q1.z,  q1.w);    // t1
    CRF_STEP(q2.z,  q2.w,  q3.x);    // t2
    CRF_STEP(q3.w,  q4.x,  q4.y);    // t3
    CRF_STEP(q5.x,  q5.y,  q5.z);    // t4
    CRF_STEP(q6.y,  q6.z,  q6.w);    // t5
    CRF_STEP(q7.z,  q7.w,  q8.x);    // t6
    CRF_STEP(q8.w,  q9.x,  q9.y);    // t7
    CRF_RENORM();
    CRF_STEP(q10.x, q10.y, q10.z);   // t8
    CRF_STEP(q11.y, q11.z, q11.w);   // t9
    CRF_STEP(q12.z, q12.w, q13.x);   // t10
    CRF_STEP(q13.w, q14.x, q14.y);   // t11
    CRF_STEP(q15.x, q15.y, q15.z);   // t12
    CRF_STEP(q16.y, q16.z, q16.w);   // t13
    CRF_STEP(q17.z, q17.w, q18.x);   // t14
    CRF_STEP(q18.w, q19.x, q19.y);   // t15
    CRF_RENORM();

    // shared tree: lanes 0-31 compose seq A, lanes 32-63 compose seq B.
    // Cross-boundary shfl pollution only reaches lanes whose results are unread.
    TREE_LEVEL(1, 0);
    TREE_LEVEL(2, 1);
    TREE_LEVEL(4, 0);
    TREE_LEVEL(8, 1);
    TREE_LEVEL(16, 1);

    // lanes 0 and 32: column 0 = full product applied to START-init vector
    float r = S0*M00 + S1*M10 + S2*M20;
    float res = __logf(r) + ls * 0.69314718055994531f;
    if (cpos == 0) out[s0 + half] = res;

#undef CRF_STEP
#undef CRF_RENORM
#undef TREE_LEVEL
}

extern "C" void kernel_launch(void* const* d_in, const int* in_sizes, int n_in,
                              void* d_out, int out_size, void* d_ws, size_t ws_size,
                              hipStream_t stream) {
    const float* feats = (const float*)d_in[0];
    const float* trans = (const float*)d_in[1];
    float* out = (float*)d_out;
    (void)d_ws; (void)ws_size;

    crf_fused<<<BB / 8, 256, 0, stream>>>(feats, trans, out);
}